// Round 1
// baseline (2580.236 us; speedup 1.0000x reference)
//
#include <hip/hip_runtime.h>

#define NTOK 100000
#define EPS 1e-5f

// ---------------------------------------------------------------------------
// GEMM (B-transposed): out[m, cbase+c] = act( sum_k A[m,k] * W[cbase+c, k] + bias )
// A: M x Ktot row-major. W: rows are output cols (row-major, length Ktot).
// Block: 256 threads = 16x16, tile 64 rows x 128 cols, 4x8 micro-tile/thread.
// Column/row interleave (tx+16j / ty+16i) keeps LDS reads broadcast/conflict-light.
// ---------------------------------------------------------------------------
template<bool RELU>
__global__ __launch_bounds__(256) void gemm_bt(
    const float* __restrict__ A, const float* __restrict__ W,
    const float* __restrict__ bias, float* __restrict__ out,
    int M, int Ktot, int ldo)
{
  __shared__ float xs[64][132];
  const int tid = threadIdx.x;
  const int tx = tid & 15, ty = tid >> 4;
  const int brow = blockIdx.x * 64;
  const int cbase = blockIdx.y * 128;

  float acc[4][8];
#pragma unroll
  for (int i = 0; i < 4; ++i)
#pragma unroll
    for (int j = 0; j < 8; ++j) acc[i][j] = 0.f;

  for (int kc = 0; kc < Ktot; kc += 128) {
#pragma unroll
    for (int t = tid; t < 2048; t += 256) {
      int r = t >> 5, c4 = t & 31;
      int row = brow + r;
      float4 v = make_float4(0.f, 0.f, 0.f, 0.f);
      if (row < M) v = *(const float4*)&A[(size_t)row * Ktot + kc + c4 * 4];
      *(float4*)&xs[r][c4 * 4] = v;
    }
    __syncthreads();
#pragma unroll 8
    for (int k4 = 0; k4 < 32; ++k4) {
      float4 a4[4];
#pragma unroll
      for (int i = 0; i < 4; ++i) a4[i] = *(const float4*)&xs[ty + 16 * i][k4 * 4];
#pragma unroll
      for (int j = 0; j < 8; ++j) {
        const int c = cbase + tx + 16 * j;
        float4 w4 = *(const float4*)&W[(size_t)c * Ktot + kc + k4 * 4];
#pragma unroll
        for (int i = 0; i < 4; ++i)
          acc[i][j] += a4[i].x * w4.x + a4[i].y * w4.y + a4[i].z * w4.z + a4[i].w * w4.w;
      }
    }
    __syncthreads();
  }

#pragma unroll
  for (int i = 0; i < 4; ++i) {
    const int row = brow + ty + 16 * i;
    if (row >= M) continue;
#pragma unroll
    for (int j = 0; j < 8; ++j) {
      const int c = cbase + tx + 16 * j;
      float v = acc[i][j] + bias[c];
      if (RELU) v = fmaxf(v, 0.f);
      out[(size_t)row * ldo + c] = v;
    }
  }
}

// ---------------------------------------------------------------------------
// GEMM (B-transposed, 128 output cols) + bias + residual + LayerNorm epilogue.
// out[m,c] = LN( resid[m,c] + sum_k A[m,k]*W[c,k] + bias[c] ) * g[c] + b[c]
// Safe for out == resid (each element is read then written by the same thread).
// ---------------------------------------------------------------------------
__global__ __launch_bounds__(256) void gemm_bt_ln(
    const float* __restrict__ A, const float* __restrict__ W,
    const float* __restrict__ bias, const float* __restrict__ resid,
    const float* __restrict__ g, const float* __restrict__ b,
    float* __restrict__ out, int M, int Ktot)
{
  __shared__ float xs[64][132];
  const int tid = threadIdx.x;
  const int tx = tid & 15, ty = tid >> 4;
  const int brow = blockIdx.x * 64;

  float acc[4][8];
#pragma unroll
  for (int i = 0; i < 4; ++i)
#pragma unroll
    for (int j = 0; j < 8; ++j) acc[i][j] = 0.f;

  for (int kc = 0; kc < Ktot; kc += 128) {
#pragma unroll
    for (int t = tid; t < 2048; t += 256) {
      int r = t >> 5, c4 = t & 31;
      int row = brow + r;
      float4 v = make_float4(0.f, 0.f, 0.f, 0.f);
      if (row < M) v = *(const float4*)&A[(size_t)row * Ktot + kc + c4 * 4];
      *(float4*)&xs[r][c4 * 4] = v;
    }
    __syncthreads();
#pragma unroll 8
    for (int k4 = 0; k4 < 32; ++k4) {
      float4 a4[4];
#pragma unroll
      for (int i = 0; i < 4; ++i) a4[i] = *(const float4*)&xs[ty + 16 * i][k4 * 4];
#pragma unroll
      for (int j = 0; j < 8; ++j) {
        const int c = tx + 16 * j;
        float4 w4 = *(const float4*)&W[(size_t)c * Ktot + kc + k4 * 4];
#pragma unroll
        for (int i = 0; i < 4; ++i)
          acc[i][j] += a4[i].x * w4.x + a4[i].y * w4.y + a4[i].z * w4.z + a4[i].w * w4.w;
      }
    }
    __syncthreads();
  }

  // epilogue: bias + residual + layernorm over the 128-wide row
#pragma unroll
  for (int i = 0; i < 4; ++i) {
    const int row = brow + ty + 16 * i;
    float psum = 0.f, psq = 0.f;
#pragma unroll
    for (int j = 0; j < 8; ++j) {
      const int c = tx + 16 * j;
      float r = (row < M) ? resid[(size_t)row * 128 + c] : 0.f;
      float v = acc[i][j] + bias[c] + r;
      acc[i][j] = v;
      psum += v;
      psq += v * v;
    }
    // reduce over the 16 lanes (same ty) that own this row
#pragma unroll
    for (int off = 1; off < 16; off <<= 1) {
      psum += __shfl_xor(psum, off, 16);
      psq  += __shfl_xor(psq,  off, 16);
    }
    const float mean = psum * (1.f / 128.f);
    const float var = psq * (1.f / 128.f) - mean * mean;
    const float rstd = rsqrtf(var + EPS);
    if (row < M) {
#pragma unroll
      for (int j = 0; j < 8; ++j) {
        const int c = tx + 16 * j;
        out[(size_t)row * 128 + c] = (acc[i][j] - mean) * rstd * g[c] + b[c];
      }
    }
  }
}

// ---------------------------------------------------------------------------
// Sampled attention: one wave per token. Lane owns dims {2l, 2l+1}; head = l/16.
// scores[h][j] = (q . k_s[j]) / sqrt(32) over the head's 32 dims -> softmax(16)
// attn[d] = sum_j w[j] * v_s[j][d]
// qkv layout: [N][384] = q | k | v
// ---------------------------------------------------------------------------
__global__ __launch_bounds__(256) void attn_kernel(
    const float* __restrict__ qkv, const int* __restrict__ samples,
    float* __restrict__ attn)
{
  const int lane = threadIdx.x & 63;
  const int wid = threadIdx.x >> 6;
  const int tok = blockIdx.x * 4 + wid;
  if (tok >= NTOK) return;

  const float scale = 0.17677669529663687f;  // 1/sqrt(32)
  float2 q2 = *(const float2*)&qkv[(size_t)tok * 384 + 2 * lane];
  q2.x *= scale;
  q2.y *= scale;

  const int myidx = samples[tok * 16 + (lane & 15)];

  float s[16];
#pragma unroll
  for (int j = 0; j < 16; ++j) {
    const int kj = __shfl(myidx, j, 16);
    const float2 k2 = *(const float2*)&qkv[(size_t)kj * 384 + 128 + 2 * lane];
    float p = q2.x * k2.x + q2.y * k2.y;
    p += __shfl_xor(p, 1, 16);
    p += __shfl_xor(p, 2, 16);
    p += __shfl_xor(p, 4, 16);
    p += __shfl_xor(p, 8, 16);
    s[j] = p;
  }

  float m = s[0];
#pragma unroll
  for (int j = 1; j < 16; ++j) m = fmaxf(m, s[j]);
  float sum = 0.f;
#pragma unroll
  for (int j = 0; j < 16; ++j) {
    s[j] = __expf(s[j] - m);
    sum += s[j];
  }
  const float inv = 1.f / sum;

  float2 a2 = make_float2(0.f, 0.f);
#pragma unroll
  for (int j = 0; j < 16; ++j) {
    const int kj = __shfl(myidx, j, 16);
    const float2 v2 = *(const float2*)&qkv[(size_t)kj * 384 + 256 + 2 * lane];
    const float wj = s[j] * inv;
    a2.x += wj * v2.x;
    a2.y += wj * v2.y;
  }
  *(float2*)&attn[(size_t)tok * 128 + 2 * lane] = a2;
}

extern "C" void kernel_launch(void* const* d_in, const int* in_sizes, int n_in,
                              void* d_out, int out_size, void* d_ws, size_t ws_size,
                              hipStream_t stream) {
  const float* x      = (const float*)d_in[0];
  const int* samples  = (const int*)d_in[1];
  const float* in_w   = (const float*)d_in[2];
  const float* in_b   = (const float*)d_in[3];
  const float* out_w  = (const float*)d_in[4];
  const float* out_b  = (const float*)d_in[5];
  const float* ffn_w1 = (const float*)d_in[6];
  const float* ffn_b1 = (const float*)d_in[7];
  const float* ffn_w2 = (const float*)d_in[8];
  const float* ffn_b2 = (const float*)d_in[9];
  const float* ln1_g  = (const float*)d_in[10];
  const float* ln1_b  = (const float*)d_in[11];
  const float* ln2_g  = (const float*)d_in[12];
  const float* ln2_b  = (const float*)d_in[13];
  float* out = (float*)d_out;

  float* ws = (float*)d_ws;
  float* qkv  = ws;                       // N x 384
  float* attn = ws + (size_t)NTOK * 384;  // N x 128
  float* h    = ws;                       // N x 512 (aliases qkv+attn; both dead by FFN1)
  float* x1   = out;                      // N x 128 (d_out doubles as x1 scratch)

  const int M = NTOK;
  dim3 blk(256);
  const int gm = (M + 63) / 64;

  // 1) QKV projection: qkv[N][384]
  gemm_bt<false><<<dim3(gm, 3), blk, 0, stream>>>(x, in_w, in_b, qkv, M, 128, 384);
  // 2) sampled attention -> attn[N][128]
  attn_kernel<<<dim3((M + 3) / 4), blk, 0, stream>>>(qkv, samples, attn);
  // 3) out-proj + residual(x) + LN1 -> x1 (in d_out)
  gemm_bt_ln<<<dim3(gm), blk, 0, stream>>>(attn, out_w, out_b, x, ln1_g, ln1_b, x1, M, 128);
  // 4) FFN1 + relu -> h[N][512]
  gemm_bt<true><<<dim3(gm, 4), blk, 0, stream>>>(x1, ffn_w1, ffn_b1, h, M, 128, 512);
  // 5) FFN2 + residual(x1) + LN2 -> out (reads x1 from d_out, writes d_out; same-thread RAW)
  gemm_bt_ln<<<dim3(gm), blk, 0, stream>>>(h, ffn_w2, ffn_b2, x1, ln2_g, ln2_b, out, M, 512);
}

// Round 2
// 372.358 us; speedup vs baseline: 6.9295x; 6.9295x over previous
//
#include <hip/hip_runtime.h>
#include <hip/hip_bf16.h>

#define NTOK 100000
#define EPS 1e-5f

using frag  = __attribute__((ext_vector_type(8))) short;  // 8 bf16 (4 VGPR)
using f32x4 = __attribute__((ext_vector_type(4))) float;
typedef __hip_bfloat16 bf16;

__device__ inline void store_val(float* p, float v) { *p = v; }
__device__ inline void store_val(bf16* p, float v) { *p = __float2bfloat16(v); }

// ---------------------------------------------------------------------------
// fp32 -> bf16 conversions
// ---------------------------------------------------------------------------
__global__ __launch_bounds__(256) void cvt_x_kernel(const float* __restrict__ in,
                                                    bf16* __restrict__ out) {
  const int t = blockIdx.x * 256 + threadIdx.x;  // 3.2M threads, 4 elems each
  const int e = t * 4;
  float4 v = *(const float4*)&in[e];
  bf16 o[4] = {__float2bfloat16(v.x), __float2bfloat16(v.y),
               __float2bfloat16(v.z), __float2bfloat16(v.w)};
  *(ulong1*)&out[e] = *(ulong1*)o;  // 8B store
}

// all four weight matrices -> one contiguous bf16 buffer
// segments (elems): in_w 49152 | out_w 16384 | ffn_w1 65536 | ffn_w2 65536
__global__ __launch_bounds__(256) void cvt_w_kernel(
    const float* __restrict__ w0, const float* __restrict__ w1,
    const float* __restrict__ w2, const float* __restrict__ w3,
    bf16* __restrict__ out) {
  const int e = (blockIdx.x * 256 + threadIdx.x) * 4;  // 49152 threads
  const float* src;
  int off;
  if (e < 49152)       { src = w0; off = 0; }
  else if (e < 65536)  { src = w1; off = 49152; }
  else if (e < 131072) { src = w2; off = 65536; }
  else                 { src = w3; off = 131072; }
  float4 v = *(const float4*)&src[e - off];
  bf16 o[4] = {__float2bfloat16(v.x), __float2bfloat16(v.y),
               __float2bfloat16(v.z), __float2bfloat16(v.w)};
  *(ulong1*)&out[e] = *(ulong1*)o;
}

// ---------------------------------------------------------------------------
// MFMA GEMM: out[m, cbase+c] = act( sum_k A[m,k] * W[cbase+c, k] + bias )
// 1 wave = 32 rows x 128 cols. A,W bf16 row-major (k contiguous). No LDS.
// A-frag: row=lane&15, k=(lane>>4)*8+i (16B contig). B-frag: col=lane&15, same k.
// C/D: col=lane&15, row=(lane>>4)*4+reg.
// ---------------------------------------------------------------------------
template<bool RELU>
__global__ __launch_bounds__(256) void mfma_gemm(
    const bf16* __restrict__ A, const bf16* __restrict__ W,
    const float* __restrict__ bias, bf16* __restrict__ out,
    int M, int Ktot, int ldo) {
  const int lane = threadIdx.x & 63;
  const int wid = threadIdx.x >> 6;
  const int row0 = blockIdx.x * 128 + wid * 32;
  if (row0 >= M) return;  // M % 32 == 0, so waves are all-or-nothing
  const int cbase = blockIdx.y * 128;
  const int lr = lane & 15;
  const int kg = lane >> 4;

  f32x4 acc[2][8] = {};
  const bf16* a0p = A + (size_t)(row0 + lr) * Ktot + kg * 8;
  const bf16* a1p = a0p + (size_t)16 * Ktot;
  const bf16* wp = W + (size_t)(cbase + lr) * Ktot + kg * 8;

  for (int kc = 0; kc < Ktot; kc += 32) {
    frag a0 = *(const frag*)(a0p + kc);
    frag a1 = *(const frag*)(a1p + kc);
#pragma unroll
    for (int j = 0; j < 8; ++j) {
      frag b = *(const frag*)(wp + (size_t)16 * j * Ktot + kc);
      acc[0][j] = __builtin_amdgcn_mfma_f32_16x16x32_bf16(a0, b, acc[0][j], 0, 0, 0);
      acc[1][j] = __builtin_amdgcn_mfma_f32_16x16x32_bf16(a1, b, acc[1][j], 0, 0, 0);
    }
  }

  float bs[8];
#pragma unroll
  for (int j = 0; j < 8; ++j) bs[j] = bias[cbase + lr + 16 * j];
#pragma unroll
  for (int i = 0; i < 2; ++i)
#pragma unroll
    for (int r = 0; r < 4; ++r) {
      const int row = row0 + i * 16 + kg * 4 + r;
      bf16* orow = out + (size_t)row * ldo + cbase + lr;
#pragma unroll
      for (int j = 0; j < 8; ++j) {
        float v = acc[i][j][r] + bs[j];
        if (RELU) v = fmaxf(v, 0.f);
        orow[16 * j] = __float2bfloat16(v);
      }
    }
}

// ---------------------------------------------------------------------------
// MFMA GEMM (N=128) + bias + bf16 residual + LayerNorm epilogue.
// Row m is held by the 16 consecutive lanes sharing lane>>4 == (m&15)>>2,
// so mean/var reduce is __shfl_xor over {1,2,4,8}.
// ---------------------------------------------------------------------------
template<typename OutT>
__global__ __launch_bounds__(256) void mfma_gemm_ln(
    const bf16* __restrict__ A, const bf16* __restrict__ W,
    const float* __restrict__ bias, const bf16* __restrict__ resid,
    const float* __restrict__ g, const float* __restrict__ b,
    OutT* __restrict__ out, int M, int Ktot) {
  const int lane = threadIdx.x & 63;
  const int wid = threadIdx.x >> 6;
  const int row0 = blockIdx.x * 128 + wid * 32;
  if (row0 >= M) return;
  const int lr = lane & 15;
  const int kg = lane >> 4;

  f32x4 acc[2][8] = {};
  const bf16* a0p = A + (size_t)(row0 + lr) * Ktot + kg * 8;
  const bf16* a1p = a0p + (size_t)16 * Ktot;
  const bf16* wp = W + (size_t)lr * Ktot + kg * 8;

  for (int kc = 0; kc < Ktot; kc += 32) {
    frag a0 = *(const frag*)(a0p + kc);
    frag a1 = *(const frag*)(a1p + kc);
#pragma unroll
    for (int j = 0; j < 8; ++j) {
      frag bb = *(const frag*)(wp + (size_t)16 * j * Ktot + kc);
      acc[0][j] = __builtin_amdgcn_mfma_f32_16x16x32_bf16(a0, bb, acc[0][j], 0, 0, 0);
      acc[1][j] = __builtin_amdgcn_mfma_f32_16x16x32_bf16(a1, bb, acc[1][j], 0, 0, 0);
    }
  }

  float bs[8], gs[8], bbs[8];
#pragma unroll
  for (int j = 0; j < 8; ++j) {
    const int c = lr + 16 * j;
    bs[j] = bias[c];
    gs[j] = g[c];
    bbs[j] = b[c];
  }

#pragma unroll
  for (int i = 0; i < 2; ++i)
#pragma unroll
    for (int r = 0; r < 4; ++r) {
      const int row = row0 + i * 16 + kg * 4 + r;
      const bf16* rrow = resid + (size_t)row * 128 + lr;
      float v[8], psum = 0.f, psq = 0.f;
#pragma unroll
      for (int j = 0; j < 8; ++j) {
        v[j] = acc[i][j][r] + bs[j] + __bfloat162float(rrow[16 * j]);
        psum += v[j];
        psq += v[j] * v[j];
      }
#pragma unroll
      for (int off = 1; off < 16; off <<= 1) {
        psum += __shfl_xor(psum, off);
        psq += __shfl_xor(psq, off);
      }
      const float mean = psum * (1.f / 128.f);
      const float var = psq * (1.f / 128.f) - mean * mean;
      const float rstd = rsqrtf(var + EPS);
      OutT* orow = out + (size_t)row * 128 + lr;
#pragma unroll
      for (int j = 0; j < 8; ++j)
        store_val(&orow[16 * j], (v[j] - mean) * rstd * gs[j] + bbs[j]);
    }
}

// ---------------------------------------------------------------------------
// Sampled attention (bf16 qkv): one wave per token, lane owns dims {2l,2l+1},
// head = lane/16. qkv layout: [N][384] = q | k | v
// ---------------------------------------------------------------------------
__global__ __launch_bounds__(256) void attn_kernel(
    const bf16* __restrict__ qkv, const int* __restrict__ samples,
    bf16* __restrict__ attn) {
  const int lane = threadIdx.x & 63;
  const int wid = threadIdx.x >> 6;
  const int tok = blockIdx.x * 4 + wid;
  if (tok >= NTOK) return;

  const float scale = 0.17677669529663687f;  // 1/sqrt(32)
  float2 q2 = __bfloat1622float2(*(const __hip_bfloat162*)&qkv[(size_t)tok * 384 + 2 * lane]);
  q2.x *= scale;
  q2.y *= scale;

  const int myidx = samples[tok * 16 + (lane & 15)];

  float s[16];
#pragma unroll
  for (int j = 0; j < 16; ++j) {
    const int kj = __shfl(myidx, j, 16);
    float2 k2 = __bfloat1622float2(*(const __hip_bfloat162*)&qkv[(size_t)kj * 384 + 128 + 2 * lane]);
    float p = q2.x * k2.x + q2.y * k2.y;
    p += __shfl_xor(p, 1, 16);
    p += __shfl_xor(p, 2, 16);
    p += __shfl_xor(p, 4, 16);
    p += __shfl_xor(p, 8, 16);
    s[j] = p;
  }

  float m = s[0];
#pragma unroll
  for (int j = 1; j < 16; ++j) m = fmaxf(m, s[j]);
  float sum = 0.f;
#pragma unroll
  for (int j = 0; j < 16; ++j) {
    s[j] = __expf(s[j] - m);
    sum += s[j];
  }
  const float inv = 1.f / sum;

  float2 a2 = make_float2(0.f, 0.f);
#pragma unroll
  for (int j = 0; j < 16; ++j) {
    const int kj = __shfl(myidx, j, 16);
    float2 v2 = __bfloat1622float2(*(const __hip_bfloat162*)&qkv[(size_t)kj * 384 + 256 + 2 * lane]);
    const float wj = s[j] * inv;
    a2.x += wj * v2.x;
    a2.y += wj * v2.y;
  }
  *(__hip_bfloat162*)&attn[(size_t)tok * 128 + 2 * lane] =
      __float22bfloat162_rn(a2);
}

extern "C" void kernel_launch(void* const* d_in, const int* in_sizes, int n_in,
                              void* d_out, int out_size, void* d_ws, size_t ws_size,
                              hipStream_t stream) {
  const float* x      = (const float*)d_in[0];
  const int* samples  = (const int*)d_in[1];
  const float* in_w   = (const float*)d_in[2];
  const float* in_b   = (const float*)d_in[3];
  const float* out_w  = (const float*)d_in[4];
  const float* out_b  = (const float*)d_in[5];
  const float* ffn_w1 = (const float*)d_in[6];
  const float* ffn_b1 = (const float*)d_in[7];
  const float* ffn_w2 = (const float*)d_in[8];
  const float* ffn_b2 = (const float*)d_in[9];
  const float* ln1_g  = (const float*)d_in[10];
  const float* ln1_b  = (const float*)d_in[11];
  const float* ln2_g  = (const float*)d_in[12];
  const float* ln2_b  = (const float*)d_in[13];
  float* out = (float*)d_out;

  // workspace layout (bytes; all 16B aligned; total ~154 MB)
  char* ws = (char*)d_ws;
  bf16* xb   = (bf16*)(ws);                  // N*128 = 25.6 MB
  bf16* qkv  = (bf16*)(ws + 25600000);       // N*384 = 76.8 MB
  bf16* attn = (bf16*)(ws + 102400000);      // N*128 = 25.6 MB
  bf16* h    = qkv;                          // N*512 = 102.4 MB (aliases qkv+attn, both dead)
  bf16* x1b  = (bf16*)(ws + 128000000);      // N*128 = 25.6 MB
  bf16* wb   = (bf16*)(ws + 153600000);      // 196608 elems = 384 KB
  bf16* in_wb   = wb;
  bf16* out_wb  = wb + 49152;
  bf16* ffn_w1b = wb + 65536;
  bf16* ffn_w2b = wb + 131072;

  const int M = NTOK;
  dim3 blk(256);
  const int gm = (M + 127) / 128;  // 782; per-block 4 waves x 32 rows

  // 0) conversions
  cvt_x_kernel<<<dim3(12500), blk, 0, stream>>>(x, xb);
  cvt_w_kernel<<<dim3(192), blk, 0, stream>>>(in_w, out_w, ffn_w1, ffn_w2, wb);
  // 1) QKV projection -> qkv[N][384] (bf16)
  mfma_gemm<false><<<dim3(gm, 3), blk, 0, stream>>>(xb, in_wb, in_b, qkv, M, 128, 384);
  // 2) sampled attention -> attn[N][128] (bf16)
  attn_kernel<<<dim3((M + 3) / 4), blk, 0, stream>>>(qkv, samples, attn);
  // 3) out-proj + residual(xb) + LN1 -> x1b (bf16)
  mfma_gemm_ln<bf16><<<dim3(gm), blk, 0, stream>>>(attn, out_wb, out_b, xb, ln1_g, ln1_b, x1b, M, 128);
  // 4) FFN1 + relu -> h[N][512] (bf16)
  mfma_gemm<true><<<dim3(gm, 4), blk, 0, stream>>>(x1b, ffn_w1b, ffn_b1, h, M, 128, 512);
  // 5) FFN2 + residual(x1b) + LN2 -> out (fp32)
  mfma_gemm_ln<float><<<dim3(gm), blk, 0, stream>>>(h, ffn_w2b, ffn_b2, x1b, ln2_g, ln2_b, out, M, 512);
}

// Round 3
// 288.051 us; speedup vs baseline: 8.9576x; 1.2927x over previous
//
#include <hip/hip_runtime.h>
#include <hip/hip_bf16.h>
#include <hip/hip_fp8.h>

#define NTOK 100000
#define EPS 1e-5f

using frag  = __attribute__((ext_vector_type(8))) short;  // 8 bf16 (4 VGPR)
using f32x4 = __attribute__((ext_vector_type(4))) float;
typedef __hip_bfloat16 bf16;

__device__ inline float bits2f(unsigned int u) { union { unsigned int i; float f; } x; x.i = u; return x.f; }
__device__ inline float bf2f(unsigned short u) { return bits2f((unsigned int)u << 16); }

__device__ inline float4 fp8x4_to_f4(unsigned int u) {
  __hip_fp8_e4m3 a, b, c, d;
  a.__x = u & 0xff; b.__x = (u >> 8) & 0xff; c.__x = (u >> 16) & 0xff; d.__x = (u >> 24) & 0xff;
  return make_float4((float)a, (float)b, (float)c, (float)d);
}
__device__ inline unsigned char f_to_fp8(float f) { __hip_fp8_e4m3 t(f); return t.__x; }

__device__ inline void store_val(float* p, float v) { *p = v; }
__device__ inline void store_val(bf16* p, float v) { *p = __float2bfloat16(v); }

// ---------------------------------------------------------------------------
// fp32 -> bf16 conversions
// ---------------------------------------------------------------------------
__global__ __launch_bounds__(256) void cvt_x_kernel(const float* __restrict__ in,
                                                    bf16* __restrict__ out) {
  const int e = (blockIdx.x * 256 + threadIdx.x) * 4;
  float4 v = *(const float4*)&in[e];
  bf16 o[4] = {__float2bfloat16(v.x), __float2bfloat16(v.y),
               __float2bfloat16(v.z), __float2bfloat16(v.w)};
  *(ulong1*)&out[e] = *(ulong1*)o;
}

__global__ __launch_bounds__(256) void cvt_w_kernel(
    const float* __restrict__ w0, const float* __restrict__ w1,
    const float* __restrict__ w2, const float* __restrict__ w3,
    bf16* __restrict__ out) {
  const int e = (blockIdx.x * 256 + threadIdx.x) * 4;
  const float* src;
  int off;
  if (e < 49152)       { src = w0; off = 0; }
  else if (e < 65536)  { src = w1; off = 49152; }
  else if (e < 131072) { src = w2; off = 65536; }
  else                 { src = w3; off = 131072; }
  float4 v = *(const float4*)&src[e - off];
  bf16 o[4] = {__float2bfloat16(v.x), __float2bfloat16(v.y),
               __float2bfloat16(v.z), __float2bfloat16(v.w)};
  *(ulong1*)&out[e] = *(ulong1*)o;
}

// ---------------------------------------------------------------------------
// MFMA GEMM: 1 wave = 64 rows x 128 cols (acc[4][8]); block = 4 waves = 256 rows.
// A,W bf16 row-major (k contiguous). No LDS; W tile served from L1/L2.
// ---------------------------------------------------------------------------
template<bool RELU>
__global__ __launch_bounds__(256) void mfma_gemm(
    const bf16* __restrict__ A, const bf16* __restrict__ W,
    const float* __restrict__ bias, bf16* __restrict__ out,
    int M, int Ktot, int ldo) {
  const int lane = threadIdx.x & 63;
  const int wid = threadIdx.x >> 6;
  const int row0 = blockIdx.x * 256 + wid * 64;
  if (row0 >= M) return;
  const int cbase = blockIdx.y * 128;
  const int lr = lane & 15, kg = lane >> 4;

  f32x4 acc[4][8] = {};
  const bf16* ap[4];
#pragma unroll
  for (int i = 0; i < 4; ++i) {
    int r = row0 + 16 * i + lr;
    if (r > M - 1) r = M - 1;  // clamp: garbage rows never stored
    ap[i] = A + (size_t)r * Ktot + kg * 8;
  }
  const bf16* wp = W + (size_t)(cbase + lr) * Ktot + kg * 8;

  for (int kc = 0; kc < Ktot; kc += 32) {
    frag a[4];
#pragma unroll
    for (int i = 0; i < 4; ++i) a[i] = *(const frag*)(ap[i] + kc);
#pragma unroll
    for (int j = 0; j < 8; ++j) {
      frag b = *(const frag*)(wp + (size_t)16 * j * Ktot + kc);
#pragma unroll
      for (int i = 0; i < 4; ++i)
        acc[i][j] = __builtin_amdgcn_mfma_f32_16x16x32_bf16(a[i], b, acc[i][j], 0, 0, 0);
    }
  }

  float bs[8];
#pragma unroll
  for (int j = 0; j < 8; ++j) bs[j] = bias[cbase + lr + 16 * j];
#pragma unroll
  for (int i = 0; i < 4; ++i)
#pragma unroll
    for (int r = 0; r < 4; ++r) {
      const int row = row0 + 16 * i + kg * 4 + r;
      if (row >= M) continue;
      bf16* orow = out + (size_t)row * ldo + cbase + lr;
#pragma unroll
      for (int j = 0; j < 8; ++j) {
        float v = acc[i][j][r] + bs[j];
        if (RELU) v = fmaxf(v, 0.f);
        orow[16 * j] = __float2bfloat16(v);
      }
    }
}

// ---------------------------------------------------------------------------
// QKV projection: same GEMM, epilogue routes blockIdx.y: 0 -> q (bf16),
// 1 -> k (fp8 e4m3), 2 -> v (fp8 e4m3). Ktot = 128.
// ---------------------------------------------------------------------------
__global__ __launch_bounds__(256) void mfma_gemm_qkv(
    const bf16* __restrict__ A, const bf16* __restrict__ W,
    const float* __restrict__ bias, bf16* __restrict__ qout,
    unsigned char* __restrict__ kout, unsigned char* __restrict__ vout, int M) {
  const int lane = threadIdx.x & 63;
  const int wid = threadIdx.x >> 6;
  const int row0 = blockIdx.x * 256 + wid * 64;
  if (row0 >= M) return;
  const int cbase = blockIdx.y * 128;
  const int lr = lane & 15, kg = lane >> 4;

  f32x4 acc[4][8] = {};
  const bf16* ap[4];
#pragma unroll
  for (int i = 0; i < 4; ++i) {
    int r = row0 + 16 * i + lr;
    if (r > M - 1) r = M - 1;
    ap[i] = A + (size_t)r * 128 + kg * 8;
  }
  const bf16* wp = W + (size_t)(cbase + lr) * 128 + kg * 8;

#pragma unroll
  for (int kc = 0; kc < 128; kc += 32) {
    frag a[4];
#pragma unroll
    for (int i = 0; i < 4; ++i) a[i] = *(const frag*)(ap[i] + kc);
#pragma unroll
    for (int j = 0; j < 8; ++j) {
      frag b = *(const frag*)(wp + (size_t)16 * j * 128 + kc);
#pragma unroll
      for (int i = 0; i < 4; ++i)
        acc[i][j] = __builtin_amdgcn_mfma_f32_16x16x32_bf16(a[i], b, acc[i][j], 0, 0, 0);
    }
  }

  float bs[8];
#pragma unroll
  for (int j = 0; j < 8; ++j) bs[j] = bias[cbase + lr + 16 * j];
  const int y = blockIdx.y;
  unsigned char* f8dst = (y == 1) ? kout : vout;
#pragma unroll
  for (int i = 0; i < 4; ++i)
#pragma unroll
    for (int r = 0; r < 4; ++r) {
      const int row = row0 + 16 * i + kg * 4 + r;
      if (row >= M) continue;
      if (y == 0) {
        bf16* orow = qout + (size_t)row * 128 + lr;
#pragma unroll
        for (int j = 0; j < 8; ++j) orow[16 * j] = __float2bfloat16(acc[i][j][r] + bs[j]);
      } else {
        unsigned char* orow = f8dst + (size_t)row * 128 + lr;
#pragma unroll
        for (int j = 0; j < 8; ++j) orow[16 * j] = f_to_fp8(acc[i][j][r] + bs[j]);
      }
    }
}

// ---------------------------------------------------------------------------
// MFMA GEMM (N=128) + bias + bf16 residual + LayerNorm. 64 rows/wave.
// ---------------------------------------------------------------------------
template<typename OutT>
__global__ __launch_bounds__(256) void mfma_gemm_ln(
    const bf16* __restrict__ A, const bf16* __restrict__ W,
    const float* __restrict__ bias, const bf16* __restrict__ resid,
    const float* __restrict__ g, const float* __restrict__ b,
    OutT* __restrict__ out, int M, int Ktot) {
  const int lane = threadIdx.x & 63;
  const int wid = threadIdx.x >> 6;
  const int row0 = blockIdx.x * 256 + wid * 64;
  if (row0 >= M) return;
  const int lr = lane & 15, kg = lane >> 4;

  f32x4 acc[4][8] = {};
  const bf16* ap[4];
#pragma unroll
  for (int i = 0; i < 4; ++i) {
    int r = row0 + 16 * i + lr;
    if (r > M - 1) r = M - 1;
    ap[i] = A + (size_t)r * Ktot + kg * 8;
  }
  const bf16* wp = W + (size_t)lr * Ktot + kg * 8;

  for (int kc = 0; kc < Ktot; kc += 32) {
    frag a[4];
#pragma unroll
    for (int i = 0; i < 4; ++i) a[i] = *(const frag*)(ap[i] + kc);
#pragma unroll
    for (int j = 0; j < 8; ++j) {
      frag bb = *(const frag*)(wp + (size_t)16 * j * Ktot + kc);
#pragma unroll
      for (int i = 0; i < 4; ++i)
        acc[i][j] = __builtin_amdgcn_mfma_f32_16x16x32_bf16(a[i], bb, acc[i][j], 0, 0, 0);
    }
  }

  float bs[8], gs[8], bbs[8];
#pragma unroll
  for (int j = 0; j < 8; ++j) {
    const int c = lr + 16 * j;
    bs[j] = bias[c]; gs[j] = g[c]; bbs[j] = b[c];
  }

#pragma unroll
  for (int i = 0; i < 4; ++i)
#pragma unroll
    for (int r = 0; r < 4; ++r) {
      const int row = row0 + 16 * i + kg * 4 + r;
      const int rr = (row > M - 1) ? (M - 1) : row;
      const bf16* rrow = resid + (size_t)rr * 128 + lr;
      float v[8], psum = 0.f, psq = 0.f;
#pragma unroll
      for (int j = 0; j < 8; ++j) {
        v[j] = acc[i][j][r] + bs[j] + __bfloat162float(rrow[16 * j]);
        psum += v[j];
        psq += v[j] * v[j];
      }
#pragma unroll
      for (int off = 1; off < 16; off <<= 1) {
        psum += __shfl_xor(psum, off);
        psq += __shfl_xor(psq, off);
      }
      const float mean = psum * (1.f / 128.f);
      const float var = psq * (1.f / 128.f) - mean * mean;
      const float rstd = rsqrtf(var + EPS);
      if (row < M) {
        OutT* orow = out + (size_t)row * 128 + lr;
#pragma unroll
        for (int j = 0; j < 8; ++j)
          store_val(&orow[16 * j], (v[j] - mean) * rstd * gs[j] + bbs[j]);
      }
    }
}

// ---------------------------------------------------------------------------
// Sampled attention, fp8 K/V. One wave per token.
// Lane l owns dims 4*(l&31)..+3; half = l>>5 selects even/odd sample of pair.
// Each uchar4 gather instruction fetches TWO 128B sample rows.
// Head = 8-lane group; score reduce shfl_xor{1,2,4}; halves merge via xor 32.
// ---------------------------------------------------------------------------
__global__ __launch_bounds__(256) void attn_kernel(
    const bf16* __restrict__ qb, const unsigned char* __restrict__ kf8,
    const unsigned char* __restrict__ vf8, const int* __restrict__ samples,
    bf16* __restrict__ attn) {
  const int lane = threadIdx.x & 63;
  const int wid = threadIdx.x >> 6;
  const int tok = blockIdx.x * 4 + wid;
  if (tok >= NTOK) return;
  const int l31 = lane & 31;
  const int half = lane >> 5;

  // q dims 4*l31..+3, pre-scaled by 1/sqrt(32)
  const float scale = 0.17677669529663687f;
  float4 q4;
  {
    ushort4 qu = *(const ushort4*)&qb[(size_t)tok * 128 + 4 * l31];
    q4 = make_float4(bf2f(qu.x) * scale, bf2f(qu.y) * scale,
                     bf2f(qu.z) * scale, bf2f(qu.w) * scale);
  }

  const int myidx = samples[tok * 16 + (lane & 15)];
  int kidx[8];
#pragma unroll
  for (int j = 0; j < 8; ++j) kidx[j] = __shfl(myidx, 2 * j + half, 16);

  float s[8];
#pragma unroll
  for (int j = 0; j < 8; ++j) {
    unsigned int ku = *(const unsigned int*)&kf8[(size_t)kidx[j] * 128 + 4 * l31];
    float4 k4 = fp8x4_to_f4(ku);
    float p = q4.x * k4.x + q4.y * k4.y + q4.z * k4.z + q4.w * k4.w;
    p += __shfl_xor(p, 1);
    p += __shfl_xor(p, 2);
    p += __shfl_xor(p, 4);
    s[j] = p;
  }

  float m = s[0];
#pragma unroll
  for (int j = 1; j < 8; ++j) m = fmaxf(m, s[j]);
  m = fmaxf(m, __shfl_xor(m, 32));
  float sum = 0.f;
#pragma unroll
  for (int j = 0; j < 8; ++j) {
    s[j] = __expf(s[j] - m);
    sum += s[j];
  }
  sum += __shfl_xor(sum, 32);
  const float inv = 1.f / sum;

  float4 a4 = make_float4(0.f, 0.f, 0.f, 0.f);
#pragma unroll
  for (int j = 0; j < 8; ++j) {
    unsigned int vu = *(const unsigned int*)&vf8[(size_t)kidx[j] * 128 + 4 * l31];
    float4 v4 = fp8x4_to_f4(vu);
    const float wj = s[j] * inv;
    a4.x += wj * v4.x; a4.y += wj * v4.y; a4.z += wj * v4.z; a4.w += wj * v4.w;
  }
  a4.x += __shfl_xor(a4.x, 32);
  a4.y += __shfl_xor(a4.y, 32);
  a4.z += __shfl_xor(a4.z, 32);
  a4.w += __shfl_xor(a4.w, 32);

  if (half == 0) {
    ushort4 o;
    o.x = __bfloat16_as_ushort(__float2bfloat16(a4.x));
    o.y = __bfloat16_as_ushort(__float2bfloat16(a4.y));
    o.z = __bfloat16_as_ushort(__float2bfloat16(a4.z));
    o.w = __bfloat16_as_ushort(__float2bfloat16(a4.w));
    *(ushort4*)&attn[(size_t)tok * 128 + 4 * l31] = o;
  }
}

extern "C" void kernel_launch(void* const* d_in, const int* in_sizes, int n_in,
                              void* d_out, int out_size, void* d_ws, size_t ws_size,
                              hipStream_t stream) {
  const float* x      = (const float*)d_in[0];
  const int* samples  = (const int*)d_in[1];
  const float* in_w   = (const float*)d_in[2];
  const float* in_b   = (const float*)d_in[3];
  const float* out_w  = (const float*)d_in[4];
  const float* out_b  = (const float*)d_in[5];
  const float* ffn_w1 = (const float*)d_in[6];
  const float* ffn_b1 = (const float*)d_in[7];
  const float* ffn_w2 = (const float*)d_in[8];
  const float* ffn_b2 = (const float*)d_in[9];
  const float* ln1_g  = (const float*)d_in[10];
  const float* ln1_b  = (const float*)d_in[11];
  const float* ln2_g  = (const float*)d_in[12];
  const float* ln2_b  = (const float*)d_in[13];
  float* out = (float*)d_out;

  // ws layout (byte offsets, all 16B aligned):
  // xb 0..25.6M | qb ..51.2M | kf8 ..64M | vf8 ..76.8M | attn ..102.4M
  // h aliases [0..102.4M] (xb/qb/kf8/vf8/attn all dead by FFN1)
  // x1b 102.4M..128M | weights 128M..128.4M
  char* ws = (char*)d_ws;
  bf16* xb   = (bf16*)(ws);
  bf16* qb   = (bf16*)(ws + 25600000);
  unsigned char* kf8 = (unsigned char*)(ws + 51200000);
  unsigned char* vf8 = (unsigned char*)(ws + 64000000);
  bf16* attn = (bf16*)(ws + 76800000);
  bf16* h    = (bf16*)(ws);
  bf16* x1b  = (bf16*)(ws + 102400000);
  bf16* wb   = (bf16*)(ws + 128000000);
  bf16* in_wb   = wb;
  bf16* out_wb  = wb + 49152;
  bf16* ffn_w1b = wb + 65536;
  bf16* ffn_w2b = wb + 131072;

  const int M = NTOK;
  dim3 blk(256);
  const int gm = (M + 255) / 256;  // 391 blocks; 4 waves x 64 rows

  cvt_x_kernel<<<dim3(12500), blk, 0, stream>>>(x, xb);
  cvt_w_kernel<<<dim3(192), blk, 0, stream>>>(in_w, out_w, ffn_w1, ffn_w2, wb);
  // 1) QKV projection -> qb (bf16), kf8/vf8 (fp8)
  mfma_gemm_qkv<<<dim3(gm, 3), blk, 0, stream>>>(xb, in_wb, in_b, qb, kf8, vf8, M);
  // 2) sampled attention -> attn (bf16)
  attn_kernel<<<dim3((M + 3) / 4), blk, 0, stream>>>(qb, kf8, vf8, samples, attn);
  // 3) out-proj + residual(xb) + LN1 -> x1b
  mfma_gemm_ln<bf16><<<dim3(gm), blk, 0, stream>>>(attn, out_wb, out_b, xb, ln1_g, ln1_b, x1b, M, 128);
  // 4) FFN1 + relu -> h[N][512]
  mfma_gemm<true><<<dim3(gm, 4), blk, 0, stream>>>(x1b, ffn_w1b, ffn_b1, h, M, 128, 512);
  // 5) FFN2 + residual(x1b) + LN2 -> out (fp32)
  mfma_gemm_ln<float><<<dim3(gm), blk, 0, stream>>>(h, ffn_w2b, ffn_b2, x1b, ln2_g, ln2_b, out, M, 512);
}